// Round 1
// baseline (3069.255 us; speedup 1.0000x reference)
//
#include <hip/hip_runtime.h>
#include <hip/hip_bf16.h>
#include <math.h>

#define BB 64
#define SS 512
#define HH 64
#define DD 128
#define NHD 8
#define ROWS (BB*SS)   // 32768

// ---------------------------------------------------------------------------
// SDE scan: one block per batch element, 256 threads, weights in registers.
// ---------------------------------------------------------------------------
__global__ __launch_bounds__(256, 1) void sde_kernel(
    const float* __restrict__ ts, const float* __restrict__ noise,
    const float* __restrict__ dW1, const float* __restrict__ db1,
    const float* __restrict__ dW2, const float* __restrict__ db2,
    const float* __restrict__ dW3, const float* __restrict__ db3,
    const float* __restrict__ gW1, const float* __restrict__ gb1,
    const float* __restrict__ gW2, const float* __restrict__ gb2,
    const float* __restrict__ pmind, const float* __restrict__ pmaxd,
    float* __restrict__ out) {
  const int b = blockIdx.x;
  const int t = threadIdx.x;
  __shared__ float sh_ty[68];     // [0..63]=y, [64]=t, [65]=h, [66]=sqrt(h)
  __shared__ float sh_h1[128];
  __shared__ float sh_g1[128];
  __shared__ float sh_h2[64];

  const float mind = fabsf(pmind[0]);
  const float maxd = fabsf(pmaxd[0]);

  const int j1 = t >> 1, half = t & 1, kb1 = half * 32;   // layer1: 128 outs, 2-way K split
  const int j2 = t >> 2, q2 = t & 3,  kb2 = q2 * 32;      // layer2: 64 outs, 4-way K split
  const int kb3 = q2 * 16;                                // layer3: 64 outs, 4-way K split

  // ---- load weights into registers (once) ----
  float wd1[33], wg1[33];
#pragma unroll
  for (int kk = 0; kk < 33; kk++) {
    // half0 covers k=0..31 (kk=32 padded to 0), half1 covers k=32..64
    bool valid = half ? true : (kk < 32);
    int k = kb1 + kk;
    wd1[kk] = valid ? dW1[k * 128 + j1] : 0.f;
    wg1[kk] = valid ? gW1[k * 128 + j1] : 0.f;
  }
  float wd2[32], wg2[32];
#pragma unroll
  for (int kk = 0; kk < 32; kk++) {
    wd2[kk] = dW2[(kb2 + kk) * 64 + j2];
    wg2[kk] = gW2[(kb2 + kk) * 64 + j2];
  }
  float wd3[16];
#pragma unroll
  for (int kk = 0; kk < 16; kk++) wd3[kk] = dW3[(kb3 + kk) * 64 + j2];

  const float b1v  = db1[j1], bg1v = gb1[j1];
  const float b2v  = db2[j2], bg2v = gb2[j2], b3v = db3[j2];

  // ---- y0 ----
  if (t < 64) {
    float y;
    if (t < 3) {
      float v = ts[b * (SS * 3) + t];           // time_series[b,0,t]
      y = fminf(fmaxf(v, 0.01f), 10.0f);
    } else {
      y = 0.1f;
    }
    sh_ty[t] = y;
    out[(long)b * (SS * HH) + t] = y;
  }

  for (int i = 0; i < SS - 1; i++) {
    if (t == 0) {
      float t0 = ts[i * 3];            // times[0][i]
      float t1 = ts[(i + 1) * 3];
      sh_ty[64] = t0;
      sh_ty[65] = t1 - t0;
      sh_ty[66] = sqrtf(t1 - t0);
    }
    __syncthreads();
    const float hh = sh_ty[65];
    const float sqh = sh_ty[66];

    // layer 1 (drift + diffusion share ty reads)
    float accd = 0.f, accg = 0.f;
#pragma unroll
    for (int kk = 0; kk < 33; kk++) {
      float v = sh_ty[kb1 + kk];
      accd += v * wd1[kk];
      accg += v * wg1[kk];
    }
    accd += __shfl_xor(accd, 1);
    accg += __shfl_xor(accg, 1);
    float h1v = tanhf(accd + b1v);
    float g1v = tanhf(accg + bg1v);
    if (!half) { sh_h1[j1] = h1v; sh_g1[j1] = g1v; }
    __syncthreads();

    // layer 2
    accd = 0.f; accg = 0.f;
#pragma unroll
    for (int kk = 0; kk < 32; kk++) {
      accd += sh_h1[kb2 + kk] * wd2[kk];
      accg += sh_g1[kb2 + kk] * wg2[kk];
    }
    accd += __shfl_xor(accd, 1); accd += __shfl_xor(accd, 2);
    accg += __shfl_xor(accg, 1); accg += __shfl_xor(accg, 2);
    float h2v = tanhf(accd + b2v);
    float xg = accg + bg2v;
    // softplus(x) = max(x,0) + log1p(exp(-|x|))
    float gcv = fmaxf(xg, 0.f) + log1pf(expf(-fabsf(xg))) + mind;
    if (q2 == 0) sh_h2[j2] = h2v;
    __syncthreads();

    // layer 3 + update
    float acc3 = 0.f;
#pragma unroll
    for (int kk = 0; kk < 16; kk++) acc3 += sh_h2[kb3 + kk] * wd3[kk];
    acc3 += __shfl_xor(acc3, 1); acc3 += __shfl_xor(acc3, 2);
    if (q2 == 0) {
      float dc = fminf(fmaxf(acc3 + b3v, -maxd), maxd);
      float yo = sh_ty[j2];
      float g = gcv * fminf(fmaxf(yo, -10.f), 10.f);
      float dwj = noise[(long)i * (BB * HH) + b * HH + j2] * sqh;
      float yn = yo + dc * yo * hh + g * dwj;
      yn = fminf(fmaxf(yn, 0.01f), 10.f);
      sh_ty[j2] = yn;
      out[(long)b * (SS * HH) + (i + 1) * HH + j2] = yn;
    }
    // next iteration's first __syncthreads orders the sh_ty writes vs reads
  }
}

// ---------------------------------------------------------------------------
// Generic fp32 GEMM: C[M,N] = A[M,K] @ W[K,N] + bias.  64x64 tile, 256 thr.
// grid = (N/64, M/64)
// ---------------------------------------------------------------------------
__global__ __launch_bounds__(256) void gemm_kernel(
    const float* __restrict__ A, const float* __restrict__ W,
    const float* __restrict__ bias, float* __restrict__ C, int K, int N) {
  __shared__ float As[16][64];
  __shared__ float Ws[16][64];
  const int t = threadIdx.x;
  const int nb = blockIdx.x * 64;
  const long mb = (long)blockIdx.y * 64;
  const int tm = t >> 4, tn = t & 15;
  const int m0 = tm * 4, n0 = tn * 4;
  const int arow = t >> 2, akq = (t & 3) * 4;
  const int wrow = t >> 4, wc = (t & 15) * 4;
  float acc[4][4] = {};

  for (int k0 = 0; k0 < K; k0 += 16) {
    float4 av = *(const float4*)&A[(mb + arow) * K + k0 + akq];
    float4 wv = *(const float4*)&W[(long)(k0 + wrow) * N + nb + wc];
    As[akq + 0][arow] = av.x;
    As[akq + 1][arow] = av.y;
    As[akq + 2][arow] = av.z;
    As[akq + 3][arow] = av.w;
    *(float4*)&Ws[wrow][wc] = wv;
    __syncthreads();
#pragma unroll
    for (int kk = 0; kk < 16; kk++) {
      float4 a4 = *(const float4*)&As[kk][m0];
      float4 b4 = *(const float4*)&Ws[kk][n0];
      acc[0][0] += a4.x * b4.x; acc[0][1] += a4.x * b4.y; acc[0][2] += a4.x * b4.z; acc[0][3] += a4.x * b4.w;
      acc[1][0] += a4.y * b4.x; acc[1][1] += a4.y * b4.y; acc[1][2] += a4.y * b4.z; acc[1][3] += a4.y * b4.w;
      acc[2][0] += a4.z * b4.x; acc[2][1] += a4.z * b4.y; acc[2][2] += a4.z * b4.z; acc[2][3] += a4.z * b4.w;
      acc[3][0] += a4.w * b4.x; acc[3][1] += a4.w * b4.y; acc[3][2] += a4.w * b4.z; acc[3][3] += a4.w * b4.w;
    }
    __syncthreads();
  }
  float4 bv = *(const float4*)&bias[nb + n0];
#pragma unroll
  for (int i = 0; i < 4; i++) {
    float4 o;
    o.x = acc[i][0] + bv.x;
    o.y = acc[i][1] + bv.y;
    o.z = acc[i][2] + bv.z;
    o.w = acc[i][3] + bv.w;
    *(float4*)&C[(mb + m0 + i) * N + nb + n0] = o;
  }
}

// ---------------------------------------------------------------------------
// Attention: one block per (b,h). K/V staged in LDS, online softmax,
// 2 query rows per thread.
// ---------------------------------------------------------------------------
__global__ __launch_bounds__(256, 1) void attn_kernel(
    const float* __restrict__ Q, const float* __restrict__ Kb,
    const float* __restrict__ Vb, float* __restrict__ O) {
  const int b = blockIdx.x >> 3, h = blockIdx.x & 7;
  __shared__ float Kt[512][16];
  __shared__ float Vt[512][16];
  const int t = threadIdx.x;
  const long base = ((long)b * SS) * DD + h * 16;

  for (int i = t; i < 2048; i += 256) {
    int row = i >> 2, seg = (i & 3) * 4;
    *(float4*)&Kt[row][seg] = *(const float4*)&Kb[base + (long)row * DD + seg];
    *(float4*)&Vt[row][seg] = *(const float4*)&Vb[base + (long)row * DD + seg];
  }
  __syncthreads();

  const int r0 = t, r1 = t + 256;
  float q0[16], q1[16];
#pragma unroll
  for (int s4 = 0; s4 < 4; s4++) {
    float4 v0 = *(const float4*)&Q[base + (long)r0 * DD + s4 * 4];
    float4 v1 = *(const float4*)&Q[base + (long)r1 * DD + s4 * 4];
    q0[s4 * 4 + 0] = v0.x; q0[s4 * 4 + 1] = v0.y; q0[s4 * 4 + 2] = v0.z; q0[s4 * 4 + 3] = v0.w;
    q1[s4 * 4 + 0] = v1.x; q1[s4 * 4 + 1] = v1.y; q1[s4 * 4 + 2] = v1.z; q1[s4 * 4 + 3] = v1.w;
  }
  float o0[16] = {}, o1[16] = {};
  float m0 = -1e30f, m1 = -1e30f, l0 = 0.f, l1 = 0.f;
  const float scale = 0.25f;  // 1/sqrt(16)

  for (int j0 = 0; j0 < SS; j0 += 16) {
    float s0[16], s1[16];
#pragma unroll
    for (int jj = 0; jj < 16; jj++) {
      const float* kr = Kt[j0 + jj];
      float a0 = 0.f, a1 = 0.f;
#pragma unroll
      for (int d = 0; d < 16; d++) {
        float kv = kr[d];
        a0 += q0[d] * kv;
        a1 += q1[d] * kv;
      }
      s0[jj] = a0 * scale;
      s1[jj] = a1 * scale;
    }
    float c0 = s0[0], c1 = s1[0];
#pragma unroll
    for (int jj = 1; jj < 16; jj++) { c0 = fmaxf(c0, s0[jj]); c1 = fmaxf(c1, s1[jj]); }
    float nm0 = fmaxf(m0, c0), nm1 = fmaxf(m1, c1);
    float cor0 = expf(m0 - nm0), cor1 = expf(m1 - nm1);
    l0 *= cor0; l1 *= cor1;
#pragma unroll
    for (int d = 0; d < 16; d++) { o0[d] *= cor0; o1[d] *= cor1; }
#pragma unroll
    for (int jj = 0; jj < 16; jj++) {
      float p0 = expf(s0[jj] - nm0);
      float p1 = expf(s1[jj] - nm1);
      l0 += p0; l1 += p1;
      const float* vr = Vt[j0 + jj];
#pragma unroll
      for (int d = 0; d < 16; d++) {
        float vv = vr[d];
        o0[d] += p0 * vv;
        o1[d] += p1 * vv;
      }
    }
    m0 = nm0; m1 = nm1;
  }
  float inv0 = 1.f / l0, inv1 = 1.f / l1;
#pragma unroll
  for (int s4 = 0; s4 < 4; s4++) {
    float4 v0, v1;
    v0.x = o0[s4 * 4 + 0] * inv0; v0.y = o0[s4 * 4 + 1] * inv0;
    v0.z = o0[s4 * 4 + 2] * inv0; v0.w = o0[s4 * 4 + 3] * inv0;
    v1.x = o1[s4 * 4 + 0] * inv1; v1.y = o1[s4 * 4 + 1] * inv1;
    v1.z = o1[s4 * 4 + 2] * inv1; v1.w = o1[s4 * 4 + 3] * inv1;
    *(float4*)&O[base + (long)r0 * DD + s4 * 4] = v0;
    *(float4*)&O[base + (long)r1 * DD + s4 * 4] = v1;
  }
}

// ---------------------------------------------------------------------------
// Residual + LayerNorm: out = LN(x + r) * gamma + beta. One wave per row.
// ---------------------------------------------------------------------------
__global__ __launch_bounds__(256) void ln_add_kernel(
    const float* __restrict__ X, const float* __restrict__ R,
    const float* __restrict__ gamma, const float* __restrict__ beta,
    float* __restrict__ Out) {
  const int t = threadIdx.x;
  const int wave = t >> 6, lane = t & 63;
  const long row = (long)blockIdx.x * 4 + wave;
  const long off = row * DD + lane * 2;
  float2 xv = *(const float2*)&X[off];
  float2 rv = *(const float2*)&R[off];
  float a0 = xv.x + rv.x, a1 = xv.y + rv.y;
  float s = a0 + a1, ss = a0 * a0 + a1 * a1;
#pragma unroll
  for (int o = 1; o < 64; o <<= 1) {
    s += __shfl_xor(s, o);
    ss += __shfl_xor(ss, o);
  }
  float mean = s * (1.f / 128.f);
  float var = ss * (1.f / 128.f) - mean * mean;
  float rstd = rsqrtf(var + 1e-5f);
  float2 o;
  o.x = (a0 - mean) * rstd * gamma[lane * 2] + beta[lane * 2];
  o.y = (a1 - mean) * rstd * gamma[lane * 2 + 1] + beta[lane * 2 + 1];
  *(float2*)&Out[off] = o;
}

// ---------------------------------------------------------------------------
// Fused FFN: out = relu(x@W1+b1)@W2+b2.  32-row tile, hidden lives in LDS.
// ---------------------------------------------------------------------------
__global__ __launch_bounds__(256, 1) void ffn_kernel(
    const float* __restrict__ X, const float* __restrict__ W1,
    const float* __restrict__ b1, const float* __restrict__ W2,
    const float* __restrict__ b2, float* __restrict__ Out) {
  __shared__ float xs[128][32];   // xT[k][r]
  __shared__ float hT[512][32];   // hiddenT[c][r]
  const int t = threadIdx.x;
  const long rbase = (long)blockIdx.x * 32;

#pragma unroll
  for (int p = 0; p < 4; p++) {
    int i = t + p * 256;
    int row = i >> 5, ks = (i & 31) * 4;
    float4 v = *(const float4*)&X[(rbase + row) * DD + ks];
    xs[ks + 0][row] = v.x;
    xs[ks + 1][row] = v.y;
    xs[ks + 2][row] = v.z;
    xs[ks + 3][row] = v.w;
  }
  __syncthreads();

  const int tr = t >> 5, tc = t & 31;
  const int r0 = tr * 4;
  {
    const int c0 = tc * 16;
    float acc[4][16] = {};
    for (int k = 0; k < 128; k++) {
      float4 xa = *(const float4*)&xs[k][r0];
      float xr[4] = {xa.x, xa.y, xa.z, xa.w};
      const float* wrow = &W1[(long)k * 512 + c0];
      float4 w0 = *(const float4*)&wrow[0];
      float4 w1 = *(const float4*)&wrow[4];
      float4 w2 = *(const float4*)&wrow[8];
      float4 w3 = *(const float4*)&wrow[12];
      float wv[16] = {w0.x, w0.y, w0.z, w0.w, w1.x, w1.y, w1.z, w1.w,
                      w2.x, w2.y, w2.z, w2.w, w3.x, w3.y, w3.z, w3.w};
#pragma unroll
      for (int c = 0; c < 16; c++) {
        float wcv = wv[c];
#pragma unroll
        for (int r = 0; r < 4; r++) acc[r][c] += xr[r] * wcv;
      }
    }
#pragma unroll
    for (int c = 0; c < 16; c++) {
      float bb = b1[c0 + c];
#pragma unroll
      for (int r = 0; r < 4; r++) hT[c0 + c][r0 + r] = fmaxf(acc[r][c] + bb, 0.f);
    }
  }
  __syncthreads();

  const int c20 = tc * 4;
  float acc2[4][4] = {};
  for (int k = 0; k < 512; k++) {
    float4 ha = *(const float4*)&hT[k][r0];
    float hr[4] = {ha.x, ha.y, ha.z, ha.w};
    float4 w = *(const float4*)&W2[(long)k * DD + c20];
    float wr[4] = {w.x, w.y, w.z, w.w};
#pragma unroll
    for (int r = 0; r < 4; r++) {
#pragma unroll
      for (int c = 0; c < 4; c++) acc2[r][c] += hr[r] * wr[c];
    }
  }
  float4 bv = *(const float4*)&b2[c20];
#pragma unroll
  for (int r = 0; r < 4; r++) {
    float4 o;
    o.x = acc2[r][0] + bv.x;
    o.y = acc2[r][1] + bv.y;
    o.z = acc2[r][2] + bv.z;
    o.w = acc2[r][3] + bv.w;
    *(float4*)&Out[(rbase + r0 + r) * DD + c20] = o;
  }
}

// ---------------------------------------------------------------------------
// Mean pool over S (mask all true -> /512)
// ---------------------------------------------------------------------------
__global__ __launch_bounds__(128) void pool_kernel(const float* __restrict__ X,
                                                   float* __restrict__ P) {
  const int b = blockIdx.x, c = threadIdx.x;
  float acc = 0.f;
  for (int s = 0; s < SS; s++) acc += X[((long)b * SS + s) * DD + c];
  P[b * DD + c] = acc * (1.f / 512.f);
}

// ---------------------------------------------------------------------------
// Classifier: logits = relu(pooled@cW1+cb1)@cW2+cb2
// ---------------------------------------------------------------------------
__global__ __launch_bounds__(64) void cls_kernel(
    const float* __restrict__ P, const float* __restrict__ W1,
    const float* __restrict__ b1, const float* __restrict__ W2,
    const float* __restrict__ b2, float* __restrict__ L) {
  const int b = blockIdx.x, t = threadIdx.x;
  __shared__ float sp[128];
  __shared__ float sh[64];
  sp[t] = P[b * DD + t];
  sp[t + 64] = P[b * DD + 64 + t];
  __syncthreads();
  float acc = b1[t];
  for (int k = 0; k < 128; k++) acc += sp[k] * W1[k * 64 + t];
  sh[t] = fmaxf(acc, 0.f);
  __syncthreads();
  if (t < 5) {
    float acc2 = b2[t];
    for (int k = 0; k < 64; k++) acc2 += sh[k] * W2[k * 5 + t];
    L[b * 5 + t] = acc2;
  }
}

// ---------------------------------------------------------------------------
extern "C" void kernel_launch(void* const* d_in, const int* in_sizes, int n_in,
                              void* d_out, int out_size, void* d_ws, size_t ws_size,
                              hipStream_t stream) {
  const float* ts    = (const float*)d_in[0];
  // d_in[1] = mask (all true) -- unused
  const float* noise = (const float*)d_in[2];
  const float* dW1   = (const float*)d_in[3];
  const float* db1   = (const float*)d_in[4];
  const float* dW2   = (const float*)d_in[5];
  const float* db2   = (const float*)d_in[6];
  const float* dW3   = (const float*)d_in[7];
  const float* db3   = (const float*)d_in[8];
  const float* gW1   = (const float*)d_in[9];
  const float* gb1   = (const float*)d_in[10];
  const float* gW2   = (const float*)d_in[11];
  const float* gb2   = (const float*)d_in[12];
  const float* mind  = (const float*)d_in[13];
  const float* maxd  = (const float*)d_in[14];
  const float* in_W  = (const float*)d_in[15];
  const float* in_b  = (const float*)d_in[16];
  const float* Wq    = (const float*)d_in[17];
  const float* bq    = (const float*)d_in[18];
  const float* Wk    = (const float*)d_in[19];
  const float* bk    = (const float*)d_in[20];
  const float* Wv    = (const float*)d_in[21];
  const float* bv    = (const float*)d_in[22];
  const float* Wo    = (const float*)d_in[23];
  const float* bo    = (const float*)d_in[24];
  const float* ln1s  = (const float*)d_in[25];
  const float* ln1b  = (const float*)d_in[26];
  const float* fW1   = (const float*)d_in[27];
  const float* fb1   = (const float*)d_in[28];
  const float* fW2   = (const float*)d_in[29];
  const float* fb2   = (const float*)d_in[30];
  const float* ln2s  = (const float*)d_in[31];
  const float* ln2b  = (const float*)d_in[32];
  const float* cW1   = (const float*)d_in[33];
  const float* cb1   = (const float*)d_in[34];
  const float* cW2   = (const float*)d_in[35];
  const float* cb2   = (const float*)d_in[36];

  float* logits = (float*)d_out;
  float* sde    = logits + BB * 5;           // 320-float offset, 16B aligned

  const long NBUF = (long)ROWS * DD;         // 4,194,304 floats
  float* bx = (float*)d_ws;
  float* bq_buf = bx + NBUF;
  float* bk_buf = bq_buf + NBUF;
  float* bv_buf = bk_buf + NBUF;
  float* bt = bv_buf + NBUF;
  float* bp = bt + NBUF;                     // pooled 64x128

  sde_kernel<<<64, 256, 0, stream>>>(ts, noise, dW1, db1, dW2, db2, dW3, db3,
                                     gW1, gb1, gW2, gb2, mind, maxd, sde);

  // x = sde @ in_W + in_b   (M=32768, K=64, N=128)
  gemm_kernel<<<dim3(2, ROWS / 64), 256, 0, stream>>>(sde, in_W, in_b, bx, 64, 128);

  for (int l = 0; l < 4; l++) {
    const float* Wq_l = Wq + (long)l * DD * DD;
    const float* Wk_l = Wk + (long)l * DD * DD;
    const float* Wv_l = Wv + (long)l * DD * DD;
    const float* Wo_l = Wo + (long)l * DD * DD;
    gemm_kernel<<<dim3(2, ROWS / 64), 256, 0, stream>>>(bx, Wq_l, bq + l * DD, bq_buf, 128, 128);
    gemm_kernel<<<dim3(2, ROWS / 64), 256, 0, stream>>>(bx, Wk_l, bk + l * DD, bk_buf, 128, 128);
    gemm_kernel<<<dim3(2, ROWS / 64), 256, 0, stream>>>(bx, Wv_l, bv + l * DD, bv_buf, 128, 128);
    attn_kernel<<<BB * NHD, 256, 0, stream>>>(bq_buf, bk_buf, bv_buf, bt);
    gemm_kernel<<<dim3(2, ROWS / 64), 256, 0, stream>>>(bt, Wo_l, bo + l * DD, bq_buf, 128, 128);
    ln_add_kernel<<<ROWS / 4, 256, 0, stream>>>(bx, bq_buf, ln1s + l * DD, ln1b + l * DD, bx);
    ffn_kernel<<<ROWS / 32, 256, 0, stream>>>(bx, fW1 + (long)l * DD * 512, fb1 + l * 512,
                                              fW2 + (long)l * 512 * DD, fb2 + l * DD, bt);
    ln_add_kernel<<<ROWS / 4, 256, 0, stream>>>(bx, bt, ln2s + l * DD, ln2b + l * DD, bx);
  }

  pool_kernel<<<BB, 128, 0, stream>>>(bx, bp);
  cls_kernel<<<BB, 64, 0, stream>>>(bp, cW1, cb1, cW2, cb2, logits);
}

// Round 2
// 1915.731 us; speedup vs baseline: 1.6021x; 1.6021x over previous
//
#include <hip/hip_runtime.h>
#include <hip/hip_bf16.h>
#include <math.h>

#define BB 64
#define SS 512
#define HH 64
#define DD 128
#define NHD 8
#define ROWS (BB*SS)   // 32768

typedef unsigned short u16;
typedef __attribute__((ext_vector_type(8))) short bf16x8;
typedef __attribute__((ext_vector_type(4))) float f32x4;

__device__ __forceinline__ u16 f2b(float f) {
  union { float f; unsigned u; } x; x.f = f;
  unsigned r = x.u + 0x7fffu + ((x.u >> 16) & 1u);
  return (u16)(r >> 16);
}

__device__ __forceinline__ float fast_tanh(float x) {
  float ax = fminf(fabsf(x), 15.f);
  float e = __expf(2.f * ax);
  float r = 1.f - __fdividef(2.f, e + 1.f);
  return copysignf(r, x);
}

// ---------------------------------------------------------------------------
// SDE scan: one block per batch. 256 threads. No global loads in the loop
// critical path (times precomputed, noise prefetched one step ahead).
// Stage A: 256 lanes -> 128 drift + 128 diffusion layer-1 outputs, no reduce.
// Stage B: 2-way k-split, one shfl_xor. Stage C: 4-way k-split, two shfl_xor.
// ---------------------------------------------------------------------------
__global__ __launch_bounds__(256, 1) void sde_kernel(
    const float* __restrict__ ts, const float* __restrict__ noise,
    const float* __restrict__ dW1, const float* __restrict__ db1,
    const float* __restrict__ dW2, const float* __restrict__ db2,
    const float* __restrict__ dW3, const float* __restrict__ db3,
    const float* __restrict__ gW1, const float* __restrict__ gb1,
    const float* __restrict__ gW2, const float* __restrict__ gb2,
    const float* __restrict__ pmind, const float* __restrict__ pmaxd,
    float* __restrict__ out) {
  const int b = blockIdx.x, t = threadIdx.x;
  __shared__ float sh_y[64];
  __shared__ float sh_h1[128], sh_g1[128];
  __shared__ float sh_h2[64], sh_gc[64];
  __shared__ float sh_tl[512], sh_hs[512], sh_sq[512];

  const float mind = fabsf(pmind[0]);
  const float maxd = fabsf(pmaxd[0]);

  // ---- per-lane register weights ----
  const int jA = t & 127;                 // layer-1 output index
  const bool drift1 = (t < 128);
  const float* W1 = drift1 ? dW1 : gW1;
  float wA[64];
#pragma unroll
  for (int k = 0; k < 64; k++) wA[k] = W1[k * 128 + jA];
  const float wAl = W1[64 * 128 + jA];
  const float bA = drift1 ? db1[jA] : gb1[jA];

  const int j2 = (t >> 1) & 63, h2half = t & 1;
  const bool drift2 = (t < 128);
  const float* W2 = drift2 ? dW2 : gW2;
  float wB[64];
#pragma unroll
  for (int k = 0; k < 64; k++) wB[k] = W2[(h2half * 64 + k) * 64 + j2];
  const float bB = drift2 ? db2[j2] : gb2[j2];

  const int j3 = t >> 2, q3 = t & 3;
  float wC[16];
#pragma unroll
  for (int k = 0; k < 16; k++) wC[k] = dW3[(q3 * 16 + k) * 64 + j3];
  const float bC = db3[j3];

  // ---- prologue: times, y0, first noise ----
  for (int i = t; i < 512; i += 256) sh_tl[i] = ts[i * 3];
  __syncthreads();
  for (int i = t; i < 511; i += 256) {
    float hh = sh_tl[i + 1] - sh_tl[i];
    sh_hs[i] = hh;
    sh_sq[i] = sqrtf(hh);
  }
  if (t < 64) {
    float y = 0.1f;
    if (t < 3) y = fminf(fmaxf(ts[b * 1536 + t], 0.01f), 10.f);
    sh_y[t] = y;
    out[(long)b * 32768 + t] = y;
  }
  float nz = 0.f;
  if (!(t & 3)) nz = noise[b * 64 + j3];
  __syncthreads();

  for (int i = 0; i < 511; i++) {
    // prefetch next step's noise (hidden behind this step's compute)
    float nzn = 0.f;
    if (!(t & 3) && i < 510) nzn = noise[(long)(i + 1) * 4096 + b * 64 + j3];
    const float tl = sh_tl[i];

    // ---- layer 1 (65 FMA, 4 accumulators, broadcast LDS reads) ----
    float a0 = 0.f, a1 = 0.f, a2 = 0.f, a3 = 0.f;
#pragma unroll
    for (int g = 0; g < 16; g++) {
      float4 yv = *(const float4*)&sh_y[g * 4];
      a0 += yv.x * wA[g * 4 + 0];
      a1 += yv.y * wA[g * 4 + 1];
      a2 += yv.z * wA[g * 4 + 2];
      a3 += yv.w * wA[g * 4 + 3];
    }
    float acc1 = (a0 + a1) + (a2 + a3) + tl * wAl + bA;
    float hv = fast_tanh(acc1);
    if (drift1) sh_h1[jA] = hv; else sh_g1[jA] = hv;
    __syncthreads();

    // ---- layer 2 (64 FMA + 1 shuffle) ----
    const float* src2 = drift2 ? sh_h1 : sh_g1;
    float c0 = 0.f, c1 = 0.f, c2 = 0.f, c3 = 0.f;
#pragma unroll
    for (int g = 0; g < 16; g++) {
      float4 xv = *(const float4*)&src2[h2half * 64 + g * 4];
      c0 += xv.x * wB[g * 4 + 0];
      c1 += xv.y * wB[g * 4 + 1];
      c2 += xv.z * wB[g * 4 + 2];
      c3 += xv.w * wB[g * 4 + 3];
    }
    float p = (c0 + c1) + (c2 + c3);
    p += __shfl_xor(p, 1);
    if (!h2half) {
      if (drift2) {
        sh_h2[j2] = fast_tanh(p + bB);
      } else {
        float xg = p + bB;
        sh_gc[j2] = fmaxf(xg, 0.f) + __logf(1.f + __expf(-fabsf(xg))) + mind;
      }
    }
    __syncthreads();

    // ---- layer 3 (16 FMA + 2 shuffles) + update ----
    float d0 = 0.f, d1 = 0.f, d2 = 0.f, d3 = 0.f;
#pragma unroll
    for (int g = 0; g < 4; g++) {
      float4 xv = *(const float4*)&sh_h2[q3 * 16 + g * 4];
      d0 += xv.x * wC[g * 4 + 0];
      d1 += xv.y * wC[g * 4 + 1];
      d2 += xv.z * wC[g * 4 + 2];
      d3 += xv.w * wC[g * 4 + 3];
    }
    float s3 = (d0 + d1) + (d2 + d3);
    s3 += __shfl_xor(s3, 1);
    s3 += __shfl_xor(s3, 2);
    if (!(t & 3)) {
      float dc = fminf(fmaxf(s3 + bC, -maxd), maxd);
      float yo = sh_y[j3];
      float g = sh_gc[j3] * fminf(fmaxf(yo, -10.f), 10.f);
      float yn = yo + dc * yo * sh_hs[i] + g * nz * sh_sq[i];
      yn = fminf(fmaxf(yn, 0.01f), 10.f);
      sh_y[j3] = yn;
      out[(long)b * 32768 + (i + 1) * 64 + j3] = yn;
    }
    nz = nzn;
    __syncthreads();
  }
}

// ---------------------------------------------------------------------------
// Weight prep: cast fp32 -> bf16 and transpose [K][N] -> [N][K].
// z: 0=in_W(64x128), 1..4=Wq/Wk/Wv/Wo(128x128 x4L), 5=fW1(128x512 x4L),
// 6=fW2(512x128 x4L)
// ---------------------------------------------------------------------------
__global__ __launch_bounds__(256) void prep_weights(
    const float* __restrict__ in_W, const float* __restrict__ Wq,
    const float* __restrict__ Wk, const float* __restrict__ Wv,
    const float* __restrict__ Wo, const float* __restrict__ fW1,
    const float* __restrict__ fW2,
    u16* __restrict__ inWt, u16* __restrict__ Wqt, u16* __restrict__ Wkt,
    u16* __restrict__ Wvt, u16* __restrict__ Wot, u16* __restrict__ fW1t,
    u16* __restrict__ fW2t) {
  const int z = blockIdx.z, layer = blockIdx.y, tile = blockIdx.x;
  const float* src; u16* dst; int R, C, nl;
  switch (z) {
    case 0: src = in_W; dst = inWt; R = 64; C = 128; nl = 1; break;
    case 1: src = Wq + layer * 16384; dst = Wqt + layer * 16384; R = 128; C = 128; nl = 4; break;
    case 2: src = Wk + layer * 16384; dst = Wkt + layer * 16384; R = 128; C = 128; nl = 4; break;
    case 3: src = Wv + layer * 16384; dst = Wvt + layer * 16384; R = 128; C = 128; nl = 4; break;
    case 4: src = Wo + layer * 16384; dst = Wot + layer * 16384; R = 128; C = 128; nl = 4; break;
    case 5: src = fW1 + layer * 65536; dst = fW1t + layer * 65536; R = 128; C = 512; nl = 4; break;
    default: src = fW2 + layer * 65536; dst = fW2t + layer * 65536; R = 512; C = 128; nl = 4; break;
  }
  const int nt = (R / 32) * (C / 32);
  if (layer >= nl || tile >= nt) return;
  const int tpr = C / 32;
  const int r0 = (tile / tpr) * 32, c0 = (tile % tpr) * 32;
  __shared__ float tl[32][33];
  const int tx = threadIdx.x & 31, ty = threadIdx.x >> 5;
#pragma unroll
  for (int p = 0; p < 4; p++)
    tl[ty + 8 * p][tx] = src[(long)(r0 + ty + 8 * p) * C + c0 + tx];
  __syncthreads();
#pragma unroll
  for (int p = 0; p < 4; p++)
    dst[(long)(c0 + ty + 8 * p) * R + r0 + tx] = f2b(tl[tx][ty + 8 * p]);
}

// ---------------------------------------------------------------------------
// fp32 -> bf16 cast, 8 elems/thread
// ---------------------------------------------------------------------------
__global__ __launch_bounds__(256) void cast_kernel(const float* __restrict__ src,
                                                   u16* __restrict__ dst) {
  const long base = ((long)blockIdx.x * 256 + threadIdx.x) * 8;
  float4 a = *(const float4*)&src[base];
  float4 b = *(const float4*)&src[base + 4];
  ushort4 o0, o1;
  o0.x = f2b(a.x); o0.y = f2b(a.y); o0.z = f2b(a.z); o0.w = f2b(a.w);
  o1.x = f2b(b.x); o1.y = f2b(b.y); o1.z = f2b(b.z); o1.w = f2b(b.w);
  *(ushort4*)&dst[base] = o0;
  *(ushort4*)&dst[base + 4] = o1;
}

// ---------------------------------------------------------------------------
// bf16 MFMA GEMM: C[M,N] = A[M,K] @ Bt[N,K]^T + bias.
// Tile 128x64, BK=32, 256 threads (4 waves as 2x2 of 64x32).
// MODE 0: fp32 out. MODE 1: bf16 out + relu. MODE 2: fp32 + bf16 out.
// ---------------------------------------------------------------------------
template <int MODE>
__global__ __launch_bounds__(256) void mfma_gemm(
    const u16* __restrict__ A, const u16* __restrict__ Bt,
    const float* __restrict__ bias, float* __restrict__ outF,
    u16* __restrict__ outB, int K, int N) {
  __shared__ u16 As[128 * 40];
  __shared__ u16 Bs[64 * 40];
  const int t = threadIdx.x;
  const int nb = blockIdx.x * 64;
  const long mb = (long)blockIdx.y * 128;
  const int lane = t & 63, wave = t >> 6;
  const int wm = (wave >> 1) * 64, wn = (wave & 1) * 32;
  const int fr = lane & 15, quad = lane >> 4;

  f32x4 zero = {0.f, 0.f, 0.f, 0.f};
  f32x4 acc[4][2];
#pragma unroll
  for (int mi = 0; mi < 4; mi++)
#pragma unroll
    for (int ni = 0; ni < 2; ni++) acc[mi][ni] = zero;

  for (int k0 = 0; k0 < K; k0 += 32) {
#pragma unroll
    for (int p = 0; p < 2; p++) {
      int idx = t + p * 256, row = idx >> 2, seg = idx & 3;
      int4 v = *(const int4*)&A[(mb + row) * K + k0 + seg * 8];
      *(int4*)&As[row * 40 + seg * 8] = v;
    }
    {
      int row = t >> 2, seg = t & 3;
      int4 v = *(const int4*)&Bt[(long)(nb + row) * K + k0 + seg * 8];
      *(int4*)&Bs[row * 40 + seg * 8] = v;
    }
    __syncthreads();
    bf16x8 af[4], bfr[2];
#pragma unroll
    for (int mi = 0; mi < 4; mi++)
      af[mi] = *(const bf16x8*)&As[(wm + mi * 16 + fr) * 40 + quad * 8];
#pragma unroll
    for (int ni = 0; ni < 2; ni++)
      bfr[ni] = *(const bf16x8*)&Bs[(wn + ni * 16 + fr) * 40 + quad * 8];
#pragma unroll
    for (int mi = 0; mi < 4; mi++)
#pragma unroll
      for (int ni = 0; ni < 2; ni++)
        acc[mi][ni] = __builtin_amdgcn_mfma_f32_16x16x32_bf16(
            af[mi], bfr[ni], acc[mi][ni], 0, 0, 0);
    __syncthreads();
  }

#pragma unroll
  for (int mi = 0; mi < 4; mi++)
#pragma unroll
    for (int ni = 0; ni < 2; ni++) {
      int col = nb + wn + ni * 16 + fr;
      float bv = bias[col];
#pragma unroll
      for (int r = 0; r < 4; r++) {
        long row = mb + wm + mi * 16 + quad * 4 + r;
        float v = acc[mi][ni][r] + bv;
        if (MODE == 0) {
          outF[row * N + col] = v;
        } else if (MODE == 1) {
          outB[row * N + col] = f2b(fmaxf(v, 0.f));
        } else {
          outF[row * N + col] = v;
          outB[row * N + col] = f2b(v);
        }
      }
    }
}

// ---------------------------------------------------------------------------
// Attention: one block per (b,h). fp32 in, bf16 out (feeds O-projection).
// ---------------------------------------------------------------------------
__global__ __launch_bounds__(256, 1) void attn_kernel(
    const float* __restrict__ Q, const float* __restrict__ Kb,
    const float* __restrict__ Vb, u16* __restrict__ O) {
  const int b = blockIdx.x >> 3, h = blockIdx.x & 7;
  __shared__ float Kt[512][16];
  __shared__ float Vt[512][16];
  const int t = threadIdx.x;
  const long base = ((long)b * SS) * DD + h * 16;

  for (int i = t; i < 2048; i += 256) {
    int row = i >> 2, seg = (i & 3) * 4;
    *(float4*)&Kt[row][seg] = *(const float4*)&Kb[base + (long)row * DD + seg];
    *(float4*)&Vt[row][seg] = *(const float4*)&Vb[base + (long)row * DD + seg];
  }
  __syncthreads();

  const int r0 = t, r1 = t + 256;
  float q0[16], q1[16];
#pragma unroll
  for (int s4 = 0; s4 < 4; s4++) {
    float4 v0 = *(const float4*)&Q[base + (long)r0 * DD + s4 * 4];
    float4 v1 = *(const float4*)&Q[base + (long)r1 * DD + s4 * 4];
    q0[s4 * 4 + 0] = v0.x; q0[s4 * 4 + 1] = v0.y; q0[s4 * 4 + 2] = v0.z; q0[s4 * 4 + 3] = v0.w;
    q1[s4 * 4 + 0] = v1.x; q1[s4 * 4 + 1] = v1.y; q1[s4 * 4 + 2] = v1.z; q1[s4 * 4 + 3] = v1.w;
  }
  float o0[16] = {}, o1[16] = {};
  float m0 = -1e30f, m1 = -1e30f, l0 = 0.f, l1 = 0.f;
  const float scale = 0.25f;

  for (int j0 = 0; j0 < SS; j0 += 16) {
    float s0[16], s1[16];
#pragma unroll
    for (int jj = 0; jj < 16; jj++) {
      const float* kr = Kt[j0 + jj];
      float a0 = 0.f, a1 = 0.f;
#pragma unroll
      for (int d = 0; d < 16; d++) {
        float kv = kr[d];
        a0 += q0[d] * kv;
        a1 += q1[d] * kv;
      }
      s0[jj] = a0 * scale;
      s1[jj] = a1 * scale;
    }
    float c0 = s0[0], c1 = s1[0];
#pragma unroll
    for (int jj = 1; jj < 16; jj++) { c0 = fmaxf(c0, s0[jj]); c1 = fmaxf(c1, s1[jj]); }
    float nm0 = fmaxf(m0, c0), nm1 = fmaxf(m1, c1);
    float cor0 = __expf(m0 - nm0), cor1 = __expf(m1 - nm1);
    l0 *= cor0; l1 *= cor1;
#pragma unroll
    for (int d = 0; d < 16; d++) { o0[d] *= cor0; o1[d] *= cor1; }
#pragma unroll
    for (int jj = 0; jj < 16; jj++) {
      float p0 = __expf(s0[jj] - nm0);
      float p1 = __expf(s1[jj] - nm1);
      l0 += p0; l1 += p1;
      const float* vr = Vt[j0 + jj];
#pragma unroll
      for (int d = 0; d < 16; d++) {
        float vv = vr[d];
        o0[d] += p0 * vv;
        o1[d] += p1 * vv;
      }
    }
    m0 = nm0; m1 = nm1;
  }
  float inv0 = __fdividef(1.f, l0), inv1 = __fdividef(1.f, l1);
#pragma unroll
  for (int s4 = 0; s4 < 4; s4++) {
    ushort4 w0, w1;
    w0.x = f2b(o0[s4 * 4 + 0] * inv0); w0.y = f2b(o0[s4 * 4 + 1] * inv0);
    w0.z = f2b(o0[s4 * 4 + 2] * inv0); w0.w = f2b(o0[s4 * 4 + 3] * inv0);
    w1.x = f2b(o1[s4 * 4 + 0] * inv1); w1.y = f2b(o1[s4 * 4 + 1] * inv1);
    w1.z = f2b(o1[s4 * 4 + 2] * inv1); w1.w = f2b(o1[s4 * 4 + 3] * inv1);
    *(ushort4*)&O[base + (long)r0 * DD + s4 * 4] = w0;
    *(ushort4*)&O[base + (long)r1 * DD + s4 * 4] = w1;
  }
}

// ---------------------------------------------------------------------------
// Residual + LayerNorm, dual fp32 + bf16 output. One wave per row.
// ---------------------------------------------------------------------------
__global__ __launch_bounds__(256) void ln_add_kernel(
    const float* __restrict__ X, const float* __restrict__ R,
    const float* __restrict__ gamma, const float* __restrict__ beta,
    float* __restrict__ Out, u16* __restrict__ OutB) {
  const int t = threadIdx.x;
  const int wave = t >> 6, lane = t & 63;
  const long row = (long)blockIdx.x * 4 + wave;
  const long off = row * DD + lane * 2;
  float2 xv = *(const float2*)&X[off];
  float2 rv = *(const float2*)&R[off];
  float a0 = xv.x + rv.x, a1 = xv.y + rv.y;
  float s = a0 + a1, ss = a0 * a0 + a1 * a1;
#pragma unroll
  for (int o = 1; o < 64; o <<= 1) {
    s += __shfl_xor(s, o);
    ss += __shfl_xor(ss, o);
  }
  float mean = s * (1.f / 128.f);
  float var = ss * (1.f / 128.f) - mean * mean;
  float rstd = rsqrtf(var + 1e-5f);
  float2 o;
  o.x = (a0 - mean) * rstd * gamma[lane * 2] + beta[lane * 2];
  o.y = (a1 - mean) * rstd * gamma[lane * 2 + 1] + beta[lane * 2 + 1];
  *(float2*)&Out[off] = o;
  ushort2 ob; ob.x = f2b(o.x); ob.y = f2b(o.y);
  *(ushort2*)&OutB[off] = ob;
}

// ---------------------------------------------------------------------------
__global__ __launch_bounds__(128) void pool_kernel(const float* __restrict__ X,
                                                   float* __restrict__ P) {
  const int b = blockIdx.x, c = threadIdx.x;
  float acc = 0.f;
  for (int s = 0; s < SS; s++) acc += X[((long)b * SS + s) * DD + c];
  P[b * DD + c] = acc * (1.f / 512.f);
}

__global__ __launch_bounds__(64) void cls_kernel(
    const float* __restrict__ P, const float* __restrict__ W1,
    const float* __restrict__ b1, const float* __restrict__ W2,
    const float* __restrict__ b2, float* __restrict__ L) {
  const int b = blockIdx.x, t = threadIdx.x;
  __shared__ float sp[128];
  __shared__ float sh[64];
  sp[t] = P[b * DD + t];
  sp[t + 64] = P[b * DD + 64 + t];
  __syncthreads();
  float acc = b1[t];
  for (int k = 0; k < 128; k++) acc += sp[k] * W1[k * 64 + t];
  sh[t] = fmaxf(acc, 0.f);
  __syncthreads();
  if (t < 5) {
    float acc2 = b2[t];
    for (int k = 0; k < 64; k++) acc2 += sh[k] * W2[k * 5 + t];
    L[b * 5 + t] = acc2;
  }
}

// ---------------------------------------------------------------------------
extern "C" void kernel_launch(void* const* d_in, const int* in_sizes, int n_in,
                              void* d_out, int out_size, void* d_ws, size_t ws_size,
                              hipStream_t stream) {
  const float* ts    = (const float*)d_in[0];
  const float* noise = (const float*)d_in[2];
  const float* dW1   = (const float*)d_in[3];
  const float* db1   = (const float*)d_in[4];
  const float* dW2   = (const float*)d_in[5];
  const float* db2   = (const float*)d_in[6];
  const float* dW3   = (const float*)d_in[7];
  const float* db3   = (const float*)d_in[8];
  const float* gW1   = (const float*)d_in[9];
  const float* gb1   = (const float*)d_in[10];
  const float* gW2   = (const float*)d_in[11];
  const float* gb2   = (const float*)d_in[12];
  const float* mind  = (const float*)d_in[13];
  const float* maxd  = (const float*)d_in[14];
  const float* in_W  = (const float*)d_in[15];
  const float* in_b  = (const float*)d_in[16];
  const float* Wq    = (const float*)d_in[17];
  const float* bq    = (const float*)d_in[18];
  const float* Wk    = (const float*)d_in[19];
  const float* bk    = (const float*)d_in[20];
  const float* Wv    = (const float*)d_in[21];
  const float* bv    = (const float*)d_in[22];
  const float* Wo    = (const float*)d_in[23];
  const float* bo    = (const float*)d_in[24];
  const float* ln1s  = (const float*)d_in[25];
  const float* ln1b  = (const float*)d_in[26];
  const float* fW1   = (const float*)d_in[27];
  const float* fb1   = (const float*)d_in[28];
  const float* fW2   = (const float*)d_in[29];
  const float* fb2   = (const float*)d_in[30];
  const float* ln2s  = (const float*)d_in[31];
  const float* ln2b  = (const float*)d_in[32];
  const float* cW1   = (const float*)d_in[33];
  const float* cb1   = (const float*)d_in[34];
  const float* cW2   = (const float*)d_in[35];
  const float* cb2   = (const float*)d_in[36];

  float* logits = (float*)d_out;
  float* sde    = logits + BB * 5;

  char* W = (char*)d_ws;
  float* bx  = (float*)(W);                        // 16 MB fp32 x
  u16*  bxb  = (u16*)(W + (16u << 20));            // 8 MB bf16 x
  float* bqf = (float*)(W + (24u << 20));          // 16 MB (Q, then O-out, then FFN-out)
  float* bkf = (float*)(W + (40u << 20));          // 16 MB (K)
  float* bvf = (float*)(W + (56u << 20));          // 16 MB (V)
  u16*  bh   = (u16*)(W + (40u << 20));            // 32 MB bf16 FFN hidden (reuses K+V)
  u16*  bob  = (u16*)(W + (72u << 20));            // 8 MB bf16 attn out
  u16*  bsb  = (u16*)(W + (80u << 20));            // 4 MB bf16 sde feats
  u16*  wts  = (u16*)(W + (84u << 20));            // ~1.6 MB bf16 weights
  float* bp  = (float*)(W + (86u << 20));          // pooled

  u16* inWt = wts;                  // [128][64]
  u16* Wqt  = inWt + 8192;          // [4][128][128]
  u16* Wkt  = Wqt + 65536;
  u16* Wvt  = Wkt + 65536;
  u16* Wot  = Wvt + 65536;
  u16* fW1t = Wot + 65536;          // [4][512][128]
  u16* fW2t = fW1t + 262144;        // [4][128][512]

  prep_weights<<<dim3(64, 4, 7), 256, 0, stream>>>(in_W, Wq, Wk, Wv, Wo, fW1, fW2,
                                                   inWt, Wqt, Wkt, Wvt, Wot, fW1t, fW2t);

  sde_kernel<<<64, 256, 0, stream>>>(ts, noise, dW1, db1, dW2, db2, dW3, db3,
                                     gW1, gb1, gW2, gb2, mind, maxd, sde);

  cast_kernel<<<1024, 256, 0, stream>>>(sde, bsb);   // 2M elems

  // x = sde @ in_W + in_b  (dual fp32+bf16 output)
  mfma_gemm<2><<<dim3(2, 256), 256, 0, stream>>>(bsb, inWt, in_b, bx, bxb, 64, 128);

  for (int l = 0; l < 4; l++) {
    mfma_gemm<0><<<dim3(2, 256), 256, 0, stream>>>(bxb, Wqt + l * 16384, bq + l * DD, bqf, nullptr, 128, 128);
    mfma_gemm<0><<<dim3(2, 256), 256, 0, stream>>>(bxb, Wkt + l * 16384, bk + l * DD, bkf, nullptr, 128, 128);
    mfma_gemm<0><<<dim3(2, 256), 256, 0, stream>>>(bxb, Wvt + l * 16384, bv + l * DD, bvf, nullptr, 128, 128);
    attn_kernel<<<BB * NHD, 256, 0, stream>>>(bqf, bkf, bvf, bob);
    mfma_gemm<0><<<dim3(2, 256), 256, 0, stream>>>(bob, Wot + l * 16384, bo + l * DD, bqf, nullptr, 128, 128);
    ln_add_kernel<<<ROWS / 4, 256, 0, stream>>>(bx, bqf, ln1s + l * DD, ln1b + l * DD, bx, bxb);
    mfma_gemm<1><<<dim3(8, 256), 256, 0, stream>>>(bxb, fW1t + l * 65536, fb1 + l * 512, nullptr, bh, 128, 512);
    mfma_gemm<0><<<dim3(2, 256), 256, 0, stream>>>(bh, fW2t + l * 65536, fb2 + l * DD, bqf, nullptr, 512, 128);
    ln_add_kernel<<<ROWS / 4, 256, 0, stream>>>(bx, bqf, ln2s + l * DD, ln2b + l * DD, bx, bxb);
  }

  pool_kernel<<<BB, 128, 0, stream>>>(bx, bp);
  cls_kernel<<<BB, 64, 0, stream>>>(bp, cW1, cb1, cW2, cb2, logits);
}

// Round 3
// 1714.046 us; speedup vs baseline: 1.7906x; 1.1177x over previous
//
#include <hip/hip_runtime.h>
#include <hip/hip_bf16.h>
#include <math.h>

#define BB 64
#define SS 512
#define HH 64
#define DD 128
#define NHD 8
#define ROWS (BB*SS)   // 32768

typedef unsigned short u16;
typedef __attribute__((ext_vector_type(8))) short bf16x8;
typedef __attribute__((ext_vector_type(4))) float f32x4;

__device__ __forceinline__ u16 f2b(float f) {
  union { float f; unsigned u; } x; x.f = f;
  unsigned r = x.u + 0x7fffu + ((x.u >> 16) & 1u);
  return (u16)(r >> 16);
}

__device__ __forceinline__ float fast_tanh(float x) {
  float ax = fminf(fabsf(x), 15.f);
  float e = __expf(2.f * ax);
  float r = 1.f - __fdividef(2.f, e + 1.f);
  return copysignf(r, x);
}

// ---------------------------------------------------------------------------
// SDE scan: one block per batch, 4 waves, 2 barriers/step.
// y replicated per wave (lane j holds y_j); per-wave LDS slice broadcasts y
// without a barrier (wave-internal LDS ordering). Stage C is computed
// redundantly by all waves so no third barrier is needed.
// ---------------------------------------------------------------------------
__global__ __launch_bounds__(256, 1) void sde_kernel(
    const float* __restrict__ ts, const float* __restrict__ noise,
    const float* __restrict__ dW1, const float* __restrict__ db1,
    const float* __restrict__ dW2, const float* __restrict__ db2,
    const float* __restrict__ dW3, const float* __restrict__ db3,
    const float* __restrict__ gW1, const float* __restrict__ gb1,
    const float* __restrict__ gW2, const float* __restrict__ gb2,
    const float* __restrict__ pmind, const float* __restrict__ pmaxd,
    float* __restrict__ out) {
  const int b = blockIdx.x, t = threadIdx.x;
  const int w = t >> 6, j = t & 63;
  __shared__ float ybc[4][64];          // per-wave y broadcast slice
  __shared__ float h1g1[256];           // h1[0..127], g1[128..255]
  __shared__ float h2s[64], gcs[64];
  __shared__ float tl_s[512], hs_s[512], sq_s[512];

  const float mind = fabsf(pmind[0]);
  const float maxd = fabsf(pmaxd[0]);

  // ---- stage-A weights: one layer-1 output per lane (K=65) ----
  const int colA = t & 127;
  const float* W1 = (t < 128) ? dW1 : gW1;
  float wA[64];
#pragma unroll
  for (int k = 0; k < 64; k++) wA[k] = W1[k * 128 + colA];
  const float wAt = W1[64 * 128 + colA];
  const float bA = (t < 128) ? db1[colA] : gb1[colA];

  // ---- stage-B weights: waves 0,1 drift h2; waves 2,3 gate gc ----
  const int oB = ((w & 1) * 32) + (j >> 1);
  const int kh = j & 1;
  const float* W2 = (w < 2) ? dW2 : gW2;
  float wB[64];
#pragma unroll
  for (int k = 0; k < 64; k++) wB[k] = W2[(kh * 64 + k) * 64 + oB];
  const float bB = (w < 2) ? db2[oB] : gb2[oB];

  // ---- stage-C weights: full column j, replicated in every wave ----
  float wC[64];
#pragma unroll
  for (int k = 0; k < 64; k++) wC[k] = dW3[k * 64 + j];
  const float bC = db3[j];

  // ---- prologue: times, y0, first noise ----
  for (int i = t; i < 512; i += 256) tl_s[i] = ts[i * 3];
  __syncthreads();
  for (int i = t; i < 511; i += 256) {
    float hh = tl_s[i + 1] - tl_s[i];
    hs_s[i] = hh;
    sq_s[i] = sqrtf(hh);
  }
  float y = 0.1f;
  if (j < 3) y = fminf(fmaxf(ts[b * 1536 + j], 0.01f), 10.f);
  if (w == 0) out[(long)b * 32768 + j] = y;
  float nz = noise[b * 64 + j];
  __syncthreads();

  for (int i = 0; i < 511; i++) {
    // prefetch next noise (all waves, redundant, coalesced)
    float nzn = 0.f;
    if (i < 510) nzn = noise[(long)(i + 1) * 4096 + b * 64 + j];
    const float tl = tl_s[i];

    // ---- stage A: layer 1, no reduction ----
    ybc[w][j] = y;
    __builtin_amdgcn_s_waitcnt(0xC07F);   // lgkmcnt(0): own-wave write visible
    float a0 = 0.f, a1 = 0.f, a2 = 0.f, a3 = 0.f;
#pragma unroll
    for (int g = 0; g < 16; g++) {
      float4 yv = *(const float4*)&ybc[w][g * 4];
      a0 += yv.x * wA[g * 4 + 0];
      a1 += yv.y * wA[g * 4 + 1];
      a2 += yv.z * wA[g * 4 + 2];
      a3 += yv.w * wA[g * 4 + 3];
    }
    float acc1 = (a0 + a1) + (a2 + a3) + tl * wAt + bA;
    h1g1[t] = fast_tanh(acc1);
    __syncthreads();                       // barrier 1

    // ---- stage B: h2 (waves 0,1) / gc (waves 2,3), pair k-split ----
    const float* srcB = h1g1 + ((w < 2) ? 0 : 128) + kh * 64;
    float c0 = 0.f, c1 = 0.f, c2 = 0.f, c3 = 0.f;
#pragma unroll
    for (int g = 0; g < 16; g++) {
      float4 xv = *(const float4*)&srcB[g * 4];
      c0 += xv.x * wB[g * 4 + 0];
      c1 += xv.y * wB[g * 4 + 1];
      c2 += xv.z * wB[g * 4 + 2];
      c3 += xv.w * wB[g * 4 + 3];
    }
    float p = (c0 + c1) + (c2 + c3);
    p += __shfl_xor(p, 1);
    if (kh == 0) {
      if (w < 2) {
        h2s[oB] = fast_tanh(p + bB);
      } else {
        float xg = p + bB;
        gcs[oB] = fmaxf(xg, 0.f) + __logf(1.f + __expf(-fabsf(xg))) + mind;
      }
    }
    __syncthreads();                       // barrier 2

    // ---- stage C: layer 3 + y update, redundant in every wave ----
    float d0 = 0.f, d1 = 0.f, d2 = 0.f, d3 = 0.f;
#pragma unroll
    for (int g = 0; g < 16; g++) {
      float4 hv = *(const float4*)&h2s[g * 4];
      d0 += hv.x * wC[g * 4 + 0];
      d1 += hv.y * wC[g * 4 + 1];
      d2 += hv.z * wC[g * 4 + 2];
      d3 += hv.w * wC[g * 4 + 3];
    }
    float s3 = (d0 + d1) + (d2 + d3);
    float dc = fminf(fmaxf(s3 + bC, -maxd), maxd);
    float gcv = gcs[j];
    float gg = gcv * fminf(fmaxf(y, -10.f), 10.f);
    float yn = y + dc * y * hs_s[i] + gg * nz * sq_s[i];
    yn = fminf(fmaxf(yn, 0.01f), 10.f);
    y = yn;
    if (w == 0) out[(long)b * 32768 + (i + 1) * 64 + j] = yn;
    nz = nzn;
    // no barrier: next stage-A touches only ybc[w]; h1g1 rewrite is
    // ordered by barrier 2 of this step, h2s/gcs rewrite by barrier 1 of
    // the next step.
  }
}

// ---------------------------------------------------------------------------
// Weight prep: cast fp32 -> bf16 and transpose [K][N] -> [N][K].
// ---------------------------------------------------------------------------
__global__ __launch_bounds__(256) void prep_weights(
    const float* __restrict__ in_W, const float* __restrict__ Wq,
    const float* __restrict__ Wk, const float* __restrict__ Wv,
    const float* __restrict__ Wo, const float* __restrict__ fW1,
    const float* __restrict__ fW2,
    u16* __restrict__ inWt, u16* __restrict__ Wqt, u16* __restrict__ Wkt,
    u16* __restrict__ Wvt, u16* __restrict__ Wot, u16* __restrict__ fW1t,
    u16* __restrict__ fW2t) {
  const int z = blockIdx.z, layer = blockIdx.y, tile = blockIdx.x;
  const float* src; u16* dst; int R, C, nl;
  switch (z) {
    case 0: src = in_W; dst = inWt; R = 64; C = 128; nl = 1; break;
    case 1: src = Wq + layer * 16384; dst = Wqt + layer * 16384; R = 128; C = 128; nl = 4; break;
    case 2: src = Wk + layer * 16384; dst = Wkt + layer * 16384; R = 128; C = 128; nl = 4; break;
    case 3: src = Wv + layer * 16384; dst = Wvt + layer * 16384; R = 128; C = 128; nl = 4; break;
    case 4: src = Wo + layer * 16384; dst = Wot + layer * 16384; R = 128; C = 128; nl = 4; break;
    case 5: src = fW1 + layer * 65536; dst = fW1t + layer * 65536; R = 128; C = 512; nl = 4; break;
    default: src = fW2 + layer * 65536; dst = fW2t + layer * 65536; R = 512; C = 128; nl = 4; break;
  }
  const int nt = (R / 32) * (C / 32);
  if (layer >= nl || tile >= nt) return;
  const int tpr = C / 32;
  const int r0 = (tile / tpr) * 32, c0 = (tile % tpr) * 32;
  __shared__ float tl[32][33];
  const int tx = threadIdx.x & 31, ty = threadIdx.x >> 5;
#pragma unroll
  for (int p = 0; p < 4; p++)
    tl[ty + 8 * p][tx] = src[(long)(r0 + ty + 8 * p) * C + c0 + tx];
  __syncthreads();
#pragma unroll
  for (int p = 0; p < 4; p++)
    dst[(long)(c0 + ty + 8 * p) * R + r0 + tx] = f2b(tl[tx][ty + 8 * p]);
}

// ---------------------------------------------------------------------------
__global__ __launch_bounds__(256) void cast_kernel(const float* __restrict__ src,
                                                   u16* __restrict__ dst) {
  const long base = ((long)blockIdx.x * 256 + threadIdx.x) * 8;
  float4 a = *(const float4*)&src[base];
  float4 b = *(const float4*)&src[base + 4];
  ushort4 o0, o1;
  o0.x = f2b(a.x); o0.y = f2b(a.y); o0.z = f2b(a.z); o0.w = f2b(a.w);
  o1.x = f2b(b.x); o1.y = f2b(b.y); o1.z = f2b(b.z); o1.w = f2b(b.w);
  *(ushort4*)&dst[base] = o0;
  *(ushort4*)&dst[base + 4] = o1;
}

// ---------------------------------------------------------------------------
// bf16 MFMA GEMM: C[M,N] = A[M,K] @ Bt[N,K]^T + bias.
// MODE 0: fp32 out. MODE 1: bf16 out + relu. MODE 2: fp32+bf16. MODE 3: bf16.
// ---------------------------------------------------------------------------
template <int MODE>
__global__ __launch_bounds__(256) void mfma_gemm(
    const u16* __restrict__ A, const u16* __restrict__ Bt,
    const float* __restrict__ bias, float* __restrict__ outF,
    u16* __restrict__ outB, int K, int N) {
  __shared__ u16 As[128 * 40];
  __shared__ u16 Bs[64 * 40];
  const int t = threadIdx.x;
  const int nb = blockIdx.x * 64;
  const long mb = (long)blockIdx.y * 128;
  const int lane = t & 63, wave = t >> 6;
  const int wm = (wave >> 1) * 64, wn = (wave & 1) * 32;
  const int fr = lane & 15, quad = lane >> 4;

  f32x4 zero = {0.f, 0.f, 0.f, 0.f};
  f32x4 acc[4][2];
#pragma unroll
  for (int mi = 0; mi < 4; mi++)
#pragma unroll
    for (int ni = 0; ni < 2; ni++) acc[mi][ni] = zero;

  for (int k0 = 0; k0 < K; k0 += 32) {
#pragma unroll
    for (int p = 0; p < 2; p++) {
      int idx = t + p * 256, row = idx >> 2, seg = idx & 3;
      int4 v = *(const int4*)&A[(mb + row) * K + k0 + seg * 8];
      *(int4*)&As[row * 40 + seg * 8] = v;
    }
    {
      int row = t >> 2, seg = t & 3;
      int4 v = *(const int4*)&Bt[(long)(nb + row) * K + k0 + seg * 8];
      *(int4*)&Bs[row * 40 + seg * 8] = v;
    }
    __syncthreads();
    bf16x8 af[4], bfr[2];
#pragma unroll
    for (int mi = 0; mi < 4; mi++)
      af[mi] = *(const bf16x8*)&As[(wm + mi * 16 + fr) * 40 + quad * 8];
#pragma unroll
    for (int ni = 0; ni < 2; ni++)
      bfr[ni] = *(const bf16x8*)&Bs[(wn + ni * 16 + fr) * 40 + quad * 8];
#pragma unroll
    for (int mi = 0; mi < 4; mi++)
#pragma unroll
      for (int ni = 0; ni < 2; ni++)
        acc[mi][ni] = __builtin_amdgcn_mfma_f32_16x16x32_bf16(
            af[mi], bfr[ni], acc[mi][ni], 0, 0, 0);
    __syncthreads();
  }

#pragma unroll
  for (int mi = 0; mi < 4; mi++)
#pragma unroll
    for (int ni = 0; ni < 2; ni++) {
      int col = nb + wn + ni * 16 + fr;
      float bv = bias[col];
#pragma unroll
      for (int r = 0; r < 4; r++) {
        long row = mb + wm + mi * 16 + quad * 4 + r;
        float v = acc[mi][ni][r] + bv;
        if (MODE == 0) {
          outF[row * N + col] = v;
        } else if (MODE == 1) {
          outB[row * N + col] = f2b(fmaxf(v, 0.f));
        } else if (MODE == 2) {
          outF[row * N + col] = v;
          outB[row * N + col] = f2b(v);
        } else {
          outB[row * N + col] = f2b(v);
        }
      }
    }
}

// ---------------------------------------------------------------------------
// Flash attention, bf16 MFMA, dh=16. One block per (b,h); wave w handles
// Q-tiles {w, w+4, ...}. Full K (LDS [key][24]) and V^T (LDS [16][520]).
// QK^T: two k-padded 16x16x32 MFMAs per 32-key tile; P transposed via
// per-wave LDS round-trip; PV: one full-K MFMA.
// ---------------------------------------------------------------------------
__global__ __launch_bounds__(256, 2) void attn_mfma(
    const u16* __restrict__ Qg, const u16* __restrict__ Kg,
    const u16* __restrict__ Vg, u16* __restrict__ Og) {
  const int bh = blockIdx.x;
  const int b = bh >> 3, h = bh & 7;
  __shared__ u16 Ks[512 * 24];
  __shared__ u16 Vt[16 * 520];
  __shared__ u16 Pb[4][16 * 40];
  const int t = threadIdx.x;
  const int w = t >> 6, lane = t & 63;
  const int m = lane & 15, quad = lane >> 4;
  const long base = ((long)b * SS) * DD + h * 16;

  for (int i = t; i < 1024; i += 256) {
    int row = i >> 1, half = i & 1;
    *(int4*)&Ks[row * 24 + half * 8] =
        *(const int4*)&Kg[base + (long)row * DD + half * 8];
    u16 v8[8];
    *(int4*)v8 = *(const int4*)&Vg[base + (long)row * DD + half * 8];
#pragma unroll
    for (int jj = 0; jj < 8; jj++) Vt[(half * 8 + jj) * 520 + row] = v8[jj];
  }
  __syncthreads();

  const float scale = 0.25f;   // 1/sqrt(16)
  for (int qt = w; qt < 32; qt += 4) {
    const int q0 = qt * 16;
    bf16x8 qf = {0, 0, 0, 0, 0, 0, 0, 0};
    if (quad < 2)
      qf = *(const bf16x8*)&Qg[base + (long)(q0 + m) * DD + quad * 8];
    f32x4 oacc = {0.f, 0.f, 0.f, 0.f};
    float mrun[4] = {-1e30f, -1e30f, -1e30f, -1e30f};
    float lrun[4] = {0.f, 0.f, 0.f, 0.f};

    for (int kt = 0; kt < 16; kt++) {
      const int k0 = kt * 32;
      bf16x8 kf0 = {0, 0, 0, 0, 0, 0, 0, 0};
      bf16x8 kf1 = {0, 0, 0, 0, 0, 0, 0, 0};
      if (quad < 2) {
        kf0 = *(const bf16x8*)&Ks[(k0 + m) * 24 + quad * 8];
        kf1 = *(const bf16x8*)&Ks[(k0 + 16 + m) * 24 + quad * 8];
      }
      f32x4 z4 = {0.f, 0.f, 0.f, 0.f};
      f32x4 slo = __builtin_amdgcn_mfma_f32_16x16x32_bf16(qf, kf0, z4, 0, 0, 0);
      f32x4 shi = __builtin_amdgcn_mfma_f32_16x16x32_bf16(qf, kf1, z4, 0, 0, 0);
      u16* pb = &Pb[w][0];
#pragma unroll
      for (int r = 0; r < 4; r++) {
        float sl = slo[r] * scale, sh = shi[r] * scale;
        float mx = fmaxf(sl, sh);
        mx = fmaxf(mx, __shfl_xor(mx, 1));
        mx = fmaxf(mx, __shfl_xor(mx, 2));
        mx = fmaxf(mx, __shfl_xor(mx, 4));
        mx = fmaxf(mx, __shfl_xor(mx, 8));
        float nm = fmaxf(mrun[r], mx);
        float alpha = __expf(mrun[r] - nm);
        mrun[r] = nm;
        float pl = __expf(sl - nm), ph = __expf(sh - nm);
        float rs = pl + ph;
        rs += __shfl_xor(rs, 1);
        rs += __shfl_xor(rs, 2);
        rs += __shfl_xor(rs, 4);
        rs += __shfl_xor(rs, 8);
        lrun[r] = lrun[r] * alpha + rs;
        oacc[r] *= alpha;
        int prow = quad * 4 + r;
        pb[prow * 40 + m] = f2b(pl);
        pb[prow * 40 + 16 + m] = f2b(ph);
      }
      __builtin_amdgcn_s_waitcnt(0xC07F);   // lgkmcnt(0): P writes visible
      bf16x8 pf = *(const bf16x8*)&pb[m * 40 + quad * 8];
      bf16x8 vf = *(const bf16x8*)&Vt[m * 520 + k0 + quad * 8];
      oacc = __builtin_amdgcn_mfma_f32_16x16x32_bf16(pf, vf, oacc, 0, 0, 0);
    }

#pragma unroll
    for (int r = 0; r < 4; r++) {
      float inv = __fdividef(1.f, lrun[r]);
      Og[base + (long)(q0 + quad * 4 + r) * DD + m] = f2b(oacc[r] * inv);
    }
  }
}

// ---------------------------------------------------------------------------
// Residual + LayerNorm, dual fp32 + bf16 output. One wave per row.
// ---------------------------------------------------------------------------
__global__ __launch_bounds__(256) void ln_add_kernel(
    const float* __restrict__ X, const float* __restrict__ R,
    const float* __restrict__ gamma, const float* __restrict__ beta,
    float* __restrict__ Out, u16* __restrict__ OutB) {
  const int t = threadIdx.x;
  const int wave = t >> 6, lane = t & 63;
  const long row = (long)blockIdx.x * 4 + wave;
  const long off = row * DD + lane * 2;
  float2 xv = *(const float2*)&X[off];
  float2 rv = *(const float2*)&R[off];
  float a0 = xv.x + rv.x, a1 = xv.y + rv.y;
  float s = a0 + a1, ss = a0 * a0 + a1 * a1;
#pragma unroll
  for (int o = 1; o < 64; o <<= 1) {
    s += __shfl_xor(s, o);
    ss += __shfl_xor(ss, o);
  }
  float mean = s * (1.f / 128.f);
  float var = ss * (1.f / 128.f) - mean * mean;
  float rstd = rsqrtf(var + 1e-5f);
  float2 o;
  o.x = (a0 - mean) * rstd * gamma[lane * 2] + beta[lane * 2];
  o.y = (a1 - mean) * rstd * gamma[lane * 2 + 1] + beta[lane * 2 + 1];
  *(float2*)&Out[off] = o;
  ushort2 ob; ob.x = f2b(o.x); ob.y = f2b(o.y);
  *(ushort2*)&OutB[off] = ob;
}

// ---------------------------------------------------------------------------
__global__ __launch_bounds__(128) void pool_kernel(const float* __restrict__ X,
                                                   float* __restrict__ P) {
  const int b = blockIdx.x, c = threadIdx.x;
  float acc = 0.f;
  for (int s = 0; s < SS; s++) acc += X[((long)b * SS + s) * DD + c];
  P[b * DD + c] = acc * (1.f / 512.f);
}

__global__ __launch_bounds__(64) void cls_kernel(
    const float* __restrict__ P, const float* __restrict__ W1,
    const float* __restrict__ b1, const float* __restrict__ W2,
    const float* __restrict__ b2, float* __restrict__ L) {
  const int b = blockIdx.x, t = threadIdx.x;
  __shared__ float sp[128];
  __shared__ float sh[64];
  sp[t] = P[b * DD + t];
  sp[t + 64] = P[b * DD + 64 + t];
  __syncthreads();
  float acc = b1[t];
  for (int k = 0; k < 128; k++) acc += sp[k] * W1[k * 64 + t];
  sh[t] = fmaxf(acc, 0.f);
  __syncthreads();
  if (t < 5) {
    float acc2 = b2[t];
    for (int k = 0; k < 64; k++) acc2 += sh[k] * W2[k * 5 + t];
    L[b * 5 + t] = acc2;
  }
}

// ---------------------------------------------------------------------------
extern "C" void kernel_launch(void* const* d_in, const int* in_sizes, int n_in,
                              void* d_out, int out_size, void* d_ws, size_t ws_size,
                              hipStream_t stream) {
  const float* ts    = (const float*)d_in[0];
  const float* noise = (const float*)d_in[2];
  const float* dW1   = (const float*)d_in[3];
  const float* db1   = (const float*)d_in[4];
  const float* dW2   = (const float*)d_in[5];
  const float* db2   = (const float*)d_in[6];
  const float* dW3   = (const float*)d_in[7];
  const float* db3   = (const float*)d_in[8];
  const float* gW1   = (const float*)d_in[9];
  const float* gb1   = (const float*)d_in[10];
  const float* gW2   = (const float*)d_in[11];
  const float* gb2   = (const float*)d_in[12];
  const float* mind  = (const float*)d_in[13];
  const float* maxd  = (const float*)d_in[14];
  const float* in_W  = (const float*)d_in[15];
  const float* in_b  = (const float*)d_in[16];
  const float* Wq    = (const float*)d_in[17];
  const float* bq    = (const float*)d_in[18];
  const float* Wk    = (const float*)d_in[19];
  const float* bk    = (const float*)d_in[20];
  const float* Wv    = (const float*)d_in[21];
  const float* bv    = (const float*)d_in[22];
  const float* Wo    = (const float*)d_in[23];
  const float* bo    = (const float*)d_in[24];
  const float* ln1s  = (const float*)d_in[25];
  const float* ln1b  = (const float*)d_in[26];
  const float* fW1   = (const float*)d_in[27];
  const float* fb1   = (const float*)d_in[28];
  const float* fW2   = (const float*)d_in[29];
  const float* fb2   = (const float*)d_in[30];
  const float* ln2s  = (const float*)d_in[31];
  const float* ln2b  = (const float*)d_in[32];
  const float* cW1   = (const float*)d_in[33];
  const float* cb1   = (const float*)d_in[34];
  const float* cW2   = (const float*)d_in[35];
  const float* cb2   = (const float*)d_in[36];

  float* logits = (float*)d_out;
  float* sde    = logits + BB * 5;

  // Workspace layout (<=80 MB; bh aliases bqb..bob after attention):
  char* W = (char*)d_ws;
  float* bx  = (float*)(W);                 // 16 MB fp32 x
  u16*  bxb  = (u16*)(W + (16u << 20));     //  8 MB bf16 x
  u16*  bqb  = (u16*)(W + (24u << 20));     //  8 MB bf16 Q
  u16*  bkb  = (u16*)(W + (32u << 20));     //  8 MB bf16 K
  u16*  bvb  = (u16*)(W + (40u << 20));     //  8 MB bf16 V
  u16*  bob  = (u16*)(W + (48u << 20));     //  8 MB bf16 attn out
  u16*  bh   = (u16*)(W + (24u << 20));     // 32 MB bf16 FFN hidden (alias)
  float* bqf = (float*)(W + (56u << 20));   // 16 MB fp32 (O-proj / FFN2 out)
  u16*  bsb  = (u16*)(W + (72u << 20));     //  4 MB bf16 sde feats
  u16*  wts  = (u16*)(W + (76u << 20));     // ~1.7 MB bf16 weights
  float* bp  = (float*)(W + (78u << 20));   // pooled

  u16* inWt = wts;                  // [128][64]
  u16* Wqt  = inWt + 8192;          // [4][128][128]
  u16* Wkt  = Wqt + 65536;
  u16* Wvt  = Wkt + 65536;
  u16* Wot  = Wvt + 65536;
  u16* fW1t = Wot + 65536;          // [4][512][128]
  u16* fW2t = fW1t + 262144;        // [4][128][512]

  prep_weights<<<dim3(64, 4, 7), 256, 0, stream>>>(in_W, Wq, Wk, Wv, Wo, fW1, fW2,
                                                   inWt, Wqt, Wkt, Wvt, Wot, fW1t, fW2t);

  sde_kernel<<<64, 256, 0, stream>>>(ts, noise, dW1, db1, dW2, db2, dW3, db3,
                                     gW1, gb1, gW2, gb2, mind, maxd, sde);

  cast_kernel<<<1024, 256, 0, stream>>>(sde, bsb);

  // x = sde @ in_W + in_b  (dual fp32+bf16 output)
  mfma_gemm<2><<<dim3(2, 256), 256, 0, stream>>>(bsb, inWt, in_b, bx, bxb, 64, 128);

  for (int l = 0; l < 4; l++) {
    mfma_gemm<3><<<dim3(2, 256), 256, 0, stream>>>(bxb, Wqt + l * 16384, bq + l * DD, nullptr, bqb, 128, 128);
    mfma_gemm<3><<<dim3(2, 256), 256, 0, stream>>>(bxb, Wkt + l * 16384, bk + l * DD, nullptr, bkb, 128, 128);
    mfma_gemm<3><<<dim3(2, 256), 256, 0, stream>>>(bxb, Wvt + l * 16384, bv + l * DD, nullptr, bvb, 128, 128);
    attn_mfma<<<BB * NHD, 256, 0, stream>>>(bqb, bkb, bvb, bob);
    mfma_gemm<0><<<dim3(2, 256), 256, 0, stream>>>(bob, Wot + l * 16384, bo + l * DD, bqf, nullptr, 128, 128);
    ln_add_kernel<<<ROWS / 4, 256, 0, stream>>>(bx, bqf, ln1s + l * DD, ln1b + l * DD, bx, bxb);
    mfma_gemm<1><<<dim3(8, 256), 256, 0, stream>>>(bxb, fW1t + l * 65536, fb1 + l * 512, nullptr, bh, 128, 512);
    mfma_gemm<0><<<dim3(2, 256), 256, 0, stream>>>(bh, fW2t + l * 65536, fb2 + l * DD, bqf, nullptr, 512, 128);
    ln_add_kernel<<<ROWS / 4, 256, 0, stream>>>(bx, bqf, ln2s + l * DD, ln2b + l * DD, bx, bxb);
  }

  pool_kernel<<<BB, 128, 0, stream>>>(bx, bp);
  cls_kernel<<<BB, 64, 0, stream>>>(bp, cW1, cb1, cW2, cb2, logits);
}